// Round 6
// baseline (691.626 us; speedup 1.0000x reference)
//
#include <hip/hip_runtime.h>
#include <hip/hip_bf16.h>

#define NN 100000
#define NE 1600000
#define DIN 128
#define NG 512
#define MAXD 64

// ================= fused: ELL fill (8 edges/thread, batched atomics) || input GEMM ====
// blocks [0, FB): fill; blocks [FB, FB+GB): h = relu(x @ W0 + b0)
#define FB 768
#define GB 512
__global__ void __launch_bounds__(256) k_build(const int4* __restrict__ src4,
                                               const int4* __restrict__ dst4,
                                               int* __restrict__ cnt,
                                               int* __restrict__ ell,
                                               const float* __restrict__ x,
                                               const float* __restrict__ W0,
                                               const float* __restrict__ b0,
                                               float* __restrict__ h) {
    __shared__ float sW[DIN * 64];
    if (blockIdx.x < FB) {
        // ---- ELL fill: pos = cnt[dst]++ ; ell[dst*64+min(pos,63)] = src ----
        int nth = FB * 256;
        for (int i = blockIdx.x * 256 + threadIdx.x; i < NE / 8; i += nth) {
            int4 s0 = src4[2 * i], s1 = src4[2 * i + 1];
            int4 d0 = dst4[2 * i], d1 = dst4[2 * i + 1];
            // 8 independent atomic chains issued back-to-back
            int p0 = atomicAdd(&cnt[d0.x], 1);
            int p1 = atomicAdd(&cnt[d0.y], 1);
            int p2 = atomicAdd(&cnt[d0.z], 1);
            int p3 = atomicAdd(&cnt[d0.w], 1);
            int p4 = atomicAdd(&cnt[d1.x], 1);
            int p5 = atomicAdd(&cnt[d1.y], 1);
            int p6 = atomicAdd(&cnt[d1.z], 1);
            int p7 = atomicAdd(&cnt[d1.w], 1);
            ell[(size_t)d0.x * MAXD + min(p0, MAXD - 1)] = s0.x;
            ell[(size_t)d0.y * MAXD + min(p1, MAXD - 1)] = s0.y;
            ell[(size_t)d0.z * MAXD + min(p2, MAXD - 1)] = s0.z;
            ell[(size_t)d0.w * MAXD + min(p3, MAXD - 1)] = s0.w;
            ell[(size_t)d1.x * MAXD + min(p4, MAXD - 1)] = s1.x;
            ell[(size_t)d1.y * MAXD + min(p5, MAXD - 1)] = s1.y;
            ell[(size_t)d1.z * MAXD + min(p6, MAXD - 1)] = s1.z;
            ell[(size_t)d1.w * MAXD + min(p7, MAXD - 1)] = s1.w;
        }
    } else {
        // ---- input GEMM: LDS weights, 2 nodes/wave ----
        for (int i = threadIdx.x; i < DIN * 64; i += 256) sW[i] = W0[i];
        __syncthreads();
        int lane = threadIdx.x & 63;
        int wv   = __builtin_amdgcn_readfirstlane(
                       (int)(((blockIdx.x - FB) * 256 + threadIdx.x) >> 6));
        int nw   = (GB * 256) >> 6;
        float bj = b0[lane];
        for (int p = wv; p < NN / 2; p += nw) {
            int n0 = 2 * p, n1 = n0 + 1;
            const float* x0 = x + (size_t)n0 * DIN;
            const float* x1 = x + (size_t)n1 * DIN;
            float acc0 = bj, acc1 = bj;
#pragma unroll 16
            for (int k = 0; k < DIN; ++k) {
                float wvl = sW[k * 64 + lane];
                acc0 = fmaf(x0[k], wvl, acc0);
                acc1 = fmaf(x1[k], wvl, acc1);
            }
            h[(size_t)n0 * 64 + lane] = fmaxf(acc0, 0.0f);
            h[(size_t)n1 * 64 + lane] = fmaxf(acc1, 0.0f);
        }
    }
}

// ================= gemmLR: g(bf16) = h@Wl ; r(fp32,in-place) = h@Wr + bl ==========
__global__ void __launch_bounds__(256, 3) k_gemmLR(float* __restrict__ h_r,
                                                   __hip_bfloat16* __restrict__ g,
                                                   const float* __restrict__ Wl,
                                                   const float* __restrict__ bl,
                                                   const float* __restrict__ Wr) {
    int lane = threadIdx.x & 63;
    float wl[64], wr[64];
#pragma unroll
    for (int k = 0; k < 64; ++k) {
        wl[k] = Wl[k * 64 + lane];
        wr[k] = Wr[k * 64 + lane];
    }
    float bj = bl[lane];
    int wv = __builtin_amdgcn_readfirstlane((int)((blockIdx.x * 256 + threadIdx.x) >> 6));
    int nw = (gridDim.x * 256) >> 6;
    for (int n = wv; n < NN; n += nw) {
        const float* hr = h_r + (size_t)n * 64;
        float l0 = 0.0f, l1 = 0.0f, r0 = 0.0f, r1 = 0.0f;
#pragma unroll
        for (int k = 0; k < 64; k += 2) {
            float s0 = hr[k], s1 = hr[k + 1];
            l0 = fmaf(s0, wl[k],     l0);
            r0 = fmaf(s0, wr[k],     r0);
            l1 = fmaf(s1, wl[k + 1], l1);
            r1 = fmaf(s1, wr[k + 1], r1);
        }
        g[(size_t)n * 64 + lane]   = __float2bfloat16(l0 + l1);
        h_r[(size_t)n * 64 + lane] = r0 + r1 + bj;
    }
}

// ================= gather: h' = relu(sum(g_bf16[src])*inv + r), 8-way ILP ==========
__global__ void __launch_bounds__(256) k_gather(const __hip_bfloat16* __restrict__ g,
                                                float* __restrict__ r_h,
                                                const int* __restrict__ cnt,
                                                const int* __restrict__ ell) {
    int lane = threadIdx.x & 63;
    int wv = __builtin_amdgcn_readfirstlane((int)((blockIdx.x * 256 + threadIdx.x) >> 6));
    int nw = (gridDim.x * 256) >> 6;
    for (int n = wv; n < NN; n += nw) {
        int dgc = cnt[n];
        int dg  = min(dgc, MAXD);
        const int* cp = ell + (size_t)n * MAXD;   // wave-uniform -> scalar loads
        float rr = r_h[(size_t)n * 64 + lane];
        float a0 = 0.0f, a1 = 0.0f, a2 = 0.0f, a3 = 0.0f;
        float a4 = 0.0f, a5 = 0.0f, a6 = 0.0f, a7 = 0.0f;
        int t = 0;
        for (; t + 8 <= dg; t += 8) {
            int s0 = cp[t],     s1 = cp[t + 1], s2 = cp[t + 2], s3 = cp[t + 3];
            int s4 = cp[t + 4], s5 = cp[t + 5], s6 = cp[t + 6], s7 = cp[t + 7];
            a0 += __bfloat162float(g[(size_t)s0 * 64 + lane]);
            a1 += __bfloat162float(g[(size_t)s1 * 64 + lane]);
            a2 += __bfloat162float(g[(size_t)s2 * 64 + lane]);
            a3 += __bfloat162float(g[(size_t)s3 * 64 + lane]);
            a4 += __bfloat162float(g[(size_t)s4 * 64 + lane]);
            a5 += __bfloat162float(g[(size_t)s5 * 64 + lane]);
            a6 += __bfloat162float(g[(size_t)s6 * 64 + lane]);
            a7 += __bfloat162float(g[(size_t)s7 * 64 + lane]);
        }
        if (t + 4 <= dg) {
            int s0 = cp[t], s1 = cp[t + 1], s2 = cp[t + 2], s3 = cp[t + 3];
            a0 += __bfloat162float(g[(size_t)s0 * 64 + lane]);
            a1 += __bfloat162float(g[(size_t)s1 * 64 + lane]);
            a2 += __bfloat162float(g[(size_t)s2 * 64 + lane]);
            a3 += __bfloat162float(g[(size_t)s3 * 64 + lane]);
            t += 4;
        }
        for (; t < dg; ++t) a0 += __bfloat162float(g[(size_t)cp[t] * 64 + lane]);
        float inv = 1.0f / fmaxf((float)dgc, 1.0f);
        float s = ((a0 + a1) + (a2 + a3)) + ((a4 + a5) + (a6 + a7));
        r_h[(size_t)n * 64 + lane] = fmaxf(fmaf(s, inv, rr), 0.0f);
    }
}

// ================= pooling (batch sorted -> run accumulate) =================
__global__ void __launch_bounds__(256) k_pool(const int* __restrict__ batch,
                                              const float* __restrict__ h,
                                              float* __restrict__ pool,
                                              float* __restrict__ cntg) {
    int lane = threadIdx.x & 63;
    int wid  = (blockIdx.x * 256 + threadIdx.x) >> 6;
    int nw   = (gridDim.x * 256) >> 6;
    int chunk = (NN + nw - 1) / nw;
    int n0 = wid * chunk;
    if (n0 >= NN) return;
    int n1 = min(n0 + chunk, NN);
    int cur = batch[n0];
    float acc = 0.0f, acc_c = 0.0f;
    for (int n = n0; n < n1; ++n) {
        int b = batch[n];
        if (b != cur) {
            atomicAdd(&pool[(size_t)cur * 64 + lane], acc);
            if (lane == 0) atomicAdd(&cntg[cur], acc_c);
            acc = 0.0f; acc_c = 0.0f; cur = b;
        }
        acc   += h[(size_t)n * 64 + lane];
        acc_c += 1.0f;
    }
    atomicAdd(&pool[(size_t)cur * 64 + lane], acc);
    if (lane == 0) atomicAdd(&cntg[cur], acc_c);
}

// ================= output GEMM =================
__global__ void __launch_bounds__(256) k_out(const float* __restrict__ pool,
                                             const float* __restrict__ cntg,
                                             const float* __restrict__ W1,
                                             const float* __restrict__ b1,
                                             float* __restrict__ out) {
    __shared__ float sW[64 * 64];
    for (int i = threadIdx.x; i < 64 * 64; i += 256) sW[i] = W1[i];
    __syncthreads();
    int lane = threadIdx.x & 63;
    int wid  = (blockIdx.x * 256 + threadIdx.x) >> 6;
    int nw   = (gridDim.x * 256) >> 6;
    for (int gidx = wid; gidx < NG; gidx += nw) {
        float ic = 1.0f / fmaxf(cntg[gidx], 1.0f);
        float acc = 0.0f;
#pragma unroll
        for (int k = 0; k < 64; ++k)
            acc = fmaf(pool[(size_t)gidx * 64 + k], sW[k * 64 + lane], acc);
        out[(size_t)gidx * 64 + lane] = fmaf(acc, ic, b1[lane]);
    }
}

extern "C" void kernel_launch(void* const* d_in, const int* in_sizes, int n_in,
                              void* d_out, int out_size, void* d_ws, size_t ws_size,
                              hipStream_t stream) {
    const float* x     = (const float*)d_in[0];
    const int*   ei    = (const int*)d_in[1];   // [2,E]
    const int*   batch = (const int*)d_in[3];
    const float* W0    = (const float*)d_in[4];
    const float* b0    = (const float*)d_in[5];
    const float* Wl    = (const float*)d_in[6];
    const float* bl    = (const float*)d_in[7];
    const float* Wr    = (const float*)d_in[8];
    const float* W1    = (const float*)d_in[9];
    const float* b1    = (const float*)d_in[10];
    float* out = (float*)d_out;

    char* ws = (char*)d_ws;
    size_t off = 0;
    auto alloc = [&](size_t bytes) -> void* {
        void* p = ws + off;
        off += (bytes + 255) & ~(size_t)255;
        return p;
    };
    float*          A   = (float*)alloc((size_t)NN * 64 * 4);          // h / r / h'
    __hip_bfloat16* G   = (__hip_bfloat16*)alloc((size_t)NN * 64 * 2); // g = h@Wl (bf16)
    int*            ell = (int*)alloc((size_t)NN * MAXD * 4);          // ELL col
    // zero region: cnt + pool + cntg contiguous
    size_t zstart = off;
    int*   cnt  = (int*)alloc((size_t)NN * 4);
    float* pool = (float*)alloc((size_t)NG * 64 * 4);
    float* cntg = (float*)alloc((size_t)NG * 4);
    size_t zlen = off - zstart;

    const int* src = ei;
    const int* dst = ei + NE;

    hipMemsetAsync(ws + zstart, 0, zlen, stream);

    // ELL fill || input projection (independent, block-partitioned)
    k_build<<<FB + GB, 256, 0, stream>>>((const int4*)src, (const int4*)dst,
                                         cnt, ell, x, W0, b0, A);

    // 3 SAGE layers: dense transform, then sparse gather
    for (int l = 0; l < 3; ++l) {
        k_gemmLR<<<1024, 256, 0, stream>>>(A, G,
                                           Wl + (size_t)l * 64 * 64,
                                           bl + (size_t)l * 64,
                                           Wr + (size_t)l * 64 * 64);
        k_gather<<<2048, 256, 0, stream>>>(G, A, cnt, ell);
    }

    k_pool<<<256, 256, 0, stream>>>(batch, A, pool, cntg);
    k_out<<<128, 256, 0, stream>>>(pool, cntg, W1, b1, out);
}

// Round 7
// 624.899 us; speedup vs baseline: 1.1068x; 1.1068x over previous
//
#include <hip/hip_runtime.h>
#include <hip/hip_bf16.h>

#define NN 100000
#define NE 1600000
#define DIN 128
#define NG 512
#define MAXD 64
#define NBUK 391               // dst>>8 buckets (256 nodes each)
#define BCAP 5120              // mean 4092, +16 sigma
#define CHUNK ((NE + NBUK - 1) / NBUK)

// ============ phase 1: bin edges by dst>>8 (LDS histogram, 1 cursor atomic per block*bucket) ====
__global__ void __launch_bounds__(512) k_bin1(const int* __restrict__ src,
                                              const int* __restrict__ dst,
                                              int* __restrict__ cursor,
                                              unsigned int* __restrict__ bucket) {
    __shared__ int lcnt[NBUK];
    __shared__ int lbase[NBUK];
    for (int i = threadIdx.x; i < NBUK; i += 512) lcnt[i] = 0;
    __syncthreads();
    int e0 = blockIdx.x * CHUNK;
    int e1 = min(e0 + CHUNK, NE);
    for (int e = e0 + (int)threadIdx.x; e < e1; e += 512)
        atomicAdd(&lcnt[dst[e] >> 8], 1);
    __syncthreads();
    for (int i = threadIdx.x; i < NBUK; i += 512) {
        int c = lcnt[i];
        lbase[i] = c ? atomicAdd(&cursor[i], c) : 0;
        lcnt[i] = 0;
    }
    __syncthreads();
    for (int e = e0 + (int)threadIdx.x; e < e1; e += 512) {
        int d = dst[e];
        int s = src[e];
        int bk = d >> 8;
        int pos = lbase[bk] + atomicAdd(&lcnt[bk], 1);
        if (pos < BCAP)
            bucket[(size_t)bk * BCAP + pos] = ((unsigned)s << 8) | (unsigned)(d & 255);
    }
}

// ============ phase 2: per-bucket ELL build with LDS position counters (no global atomics) ====
__global__ void __launch_bounds__(256) k_bin2(const unsigned int* __restrict__ bucket,
                                              const int* __restrict__ cursor,
                                              int* __restrict__ cnt,
                                              int* __restrict__ ell) {
    __shared__ int lc[256];
    lc[threadIdx.x] = 0;
    __syncthreads();
    int b = blockIdx.x;
    int m = min(cursor[b], BCAP);
    const unsigned int* bp = bucket + (size_t)b * BCAP;
    for (int i = threadIdx.x; i < m; i += 256) {
        unsigned v = bp[i];
        int dlo = (int)(v & 255u);
        int s   = (int)(v >> 8);
        int p   = atomicAdd(&lc[dlo], 1);     // LDS atomic
        if (p < MAXD)
            ell[(((size_t)b << 8) + dlo) * MAXD + p] = s;
    }
    __syncthreads();
    int n = (b << 8) + (int)threadIdx.x;
    if (n < NN) cnt[n] = lc[threadIdx.x];
}

// ============ input GEMM: h = relu(x @ W0 + b0), LDS weights, 2 nodes/wave ============
__global__ void __launch_bounds__(512) k_in_gemm(const float* __restrict__ x,
                                                 const float* __restrict__ W0,
                                                 const float* __restrict__ b0,
                                                 float* __restrict__ h) {
    __shared__ float sW[DIN * 64];
    for (int i = threadIdx.x; i < DIN * 64; i += 512) sW[i] = W0[i];
    __syncthreads();
    int lane = threadIdx.x & 63;
    int wv   = __builtin_amdgcn_readfirstlane((int)((blockIdx.x * 512 + threadIdx.x) >> 6));
    int nw   = (gridDim.x * 512) >> 6;
    float bj = b0[lane];
    for (int p = wv; p < NN / 2; p += nw) {
        int n0 = 2 * p, n1 = n0 + 1;
        const float* x0 = x + (size_t)n0 * DIN;
        const float* x1 = x + (size_t)n1 * DIN;
        float acc0 = bj, acc1 = bj;
#pragma unroll 16
        for (int k = 0; k < DIN; ++k) {
            float wvl = sW[k * 64 + lane];
            acc0 = fmaf(x0[k], wvl, acc0);
            acc1 = fmaf(x1[k], wvl, acc1);
        }
        h[(size_t)n0 * 64 + lane] = fmaxf(acc0, 0.0f);
        h[(size_t)n1 * 64 + lane] = fmaxf(acc1, 0.0f);
    }
}

// ============ gemmLR: g(bf16) = h@Wl ; r(fp32,in-place) = h@Wr + bl ============
__global__ void __launch_bounds__(256, 3) k_gemmLR(float* __restrict__ h_r,
                                                   __hip_bfloat16* __restrict__ g,
                                                   const float* __restrict__ Wl,
                                                   const float* __restrict__ bl,
                                                   const float* __restrict__ Wr) {
    int lane = threadIdx.x & 63;
    float wl[64], wr[64];
#pragma unroll
    for (int k = 0; k < 64; ++k) {
        wl[k] = Wl[k * 64 + lane];
        wr[k] = Wr[k * 64 + lane];
    }
    float bj = bl[lane];
    int wv = __builtin_amdgcn_readfirstlane((int)((blockIdx.x * 256 + threadIdx.x) >> 6));
    int nw = (gridDim.x * 256) >> 6;
    for (int n = wv; n < NN; n += nw) {
        const float* hr = h_r + (size_t)n * 64;
        float l0 = 0.0f, l1 = 0.0f, r0 = 0.0f, r1 = 0.0f;
#pragma unroll
        for (int k = 0; k < 64; k += 2) {
            float s0 = hr[k], s1 = hr[k + 1];
            l0 = fmaf(s0, wl[k],     l0);
            r0 = fmaf(s0, wr[k],     r0);
            l1 = fmaf(s1, wl[k + 1], l1);
            r1 = fmaf(s1, wr[k + 1], r1);
        }
        g[(size_t)n * 64 + lane]   = __float2bfloat16(l0 + l1);
        h_r[(size_t)n * 64 + lane] = r0 + r1 + bj;
    }
}

// ============ gather: 2 nodes/wave, 4 B/lane (bf16x2), vector indices + shfl ============
// half 0 (lanes 0-31) = node 2p, half 1 = node 2p+1; lane owns features {2col, 2col+1}.
__global__ void __launch_bounds__(256) k_gather(const unsigned int* __restrict__ g2,
                                                float* __restrict__ r_h,
                                                const int* __restrict__ cnt,
                                                const int* __restrict__ ell) {
    int lane = threadIdx.x & 63;
    int half = lane >> 5;
    int col  = lane & 31;
    int wv = __builtin_amdgcn_readfirstlane((int)((blockIdx.x * 256 + threadIdx.x) >> 6));
    int nw = (gridDim.x * 256) >> 6;
    for (int p = wv; p < NN / 2; p += nw) {
        int nA = 2 * p, nB = nA + 1;
        int dgA = cnt[nA], dgB = cnt[nB];            // wave-uniform scalar loads
        int myn   = half ? nB : nA;
        int mydg  = half ? dgB : dgA;
        int mydgc = min(mydg, MAXD);
        int maxdg = min(max(dgA, dgB), MAXD);
        float L0 = 0.f, L1 = 0.f, L2 = 0.f, L3 = 0.f;
        float H0 = 0.f, H1 = 0.f, H2 = 0.f, H3 = 0.f;
        for (int c = 0; c < maxdg; c += 32) {
            int idxv = 0;
            if (c + col < mydgc)
                idxv = ell[(size_t)myn * MAXD + c + col];   // coalesced 2x128B
            int lim = min(maxdg - c, 32);
            int j = 0;
            for (; j + 4 <= lim; j += 4) {
                int i0 = __shfl(idxv, half * 32 + j);
                int i1 = __shfl(idxv, half * 32 + j + 1);
                int i2 = __shfl(idxv, half * 32 + j + 2);
                int i3 = __shfl(idxv, half * 32 + j + 3);
                if (c + j     < mydgc) { unsigned u = g2[(size_t)i0 * 32 + col];
                    L0 += __uint_as_float(u << 16); H0 += __uint_as_float(u & 0xffff0000u); }
                if (c + j + 1 < mydgc) { unsigned u = g2[(size_t)i1 * 32 + col];
                    L1 += __uint_as_float(u << 16); H1 += __uint_as_float(u & 0xffff0000u); }
                if (c + j + 2 < mydgc) { unsigned u = g2[(size_t)i2 * 32 + col];
                    L2 += __uint_as_float(u << 16); H2 += __uint_as_float(u & 0xffff0000u); }
                if (c + j + 3 < mydgc) { unsigned u = g2[(size_t)i3 * 32 + col];
                    L3 += __uint_as_float(u << 16); H3 += __uint_as_float(u & 0xffff0000u); }
            }
            for (; j < lim; ++j) {
                int i0 = __shfl(idxv, half * 32 + j);
                if (c + j < mydgc) { unsigned u = g2[(size_t)i0 * 32 + col];
                    L0 += __uint_as_float(u << 16); H0 += __uint_as_float(u & 0xffff0000u); }
            }
        }
        float inv  = 1.0f / fmaxf((float)mydg, 1.0f);
        float sumL = (L0 + L1) + (L2 + L3);
        float sumH = (H0 + H1) + (H2 + H3);
        float2* rp = (float2*)r_h + (size_t)myn * 32 + col;
        float2 rv = *rp;
        rv.x = fmaxf(fmaf(sumL, inv, rv.x), 0.0f);
        rv.y = fmaxf(fmaf(sumH, inv, rv.y), 0.0f);
        *rp = rv;
    }
}

// ============ pooling (batch sorted -> run accumulate) ============
__global__ void __launch_bounds__(256) k_pool(const int* __restrict__ batch,
                                              const float* __restrict__ h,
                                              float* __restrict__ pool,
                                              float* __restrict__ cntg) {
    int lane = threadIdx.x & 63;
    int wid  = (blockIdx.x * 256 + threadIdx.x) >> 6;
    int nw   = (gridDim.x * 256) >> 6;
    int chunk = (NN + nw - 1) / nw;
    int n0 = wid * chunk;
    if (n0 >= NN) return;
    int n1 = min(n0 + chunk, NN);
    int cur = batch[n0];
    float acc = 0.0f, acc_c = 0.0f;
    for (int n = n0; n < n1; ++n) {
        int b = batch[n];
        if (b != cur) {
            atomicAdd(&pool[(size_t)cur * 64 + lane], acc);
            if (lane == 0) atomicAdd(&cntg[cur], acc_c);
            acc = 0.0f; acc_c = 0.0f; cur = b;
        }
        acc   += h[(size_t)n * 64 + lane];
        acc_c += 1.0f;
    }
    atomicAdd(&pool[(size_t)cur * 64 + lane], acc);
    if (lane == 0) atomicAdd(&cntg[cur], acc_c);
}

// ============ output GEMM ============
__global__ void __launch_bounds__(256) k_out(const float* __restrict__ pool,
                                             const float* __restrict__ cntg,
                                             const float* __restrict__ W1,
                                             const float* __restrict__ b1,
                                             float* __restrict__ out) {
    __shared__ float sW[64 * 64];
    for (int i = threadIdx.x; i < 64 * 64; i += 256) sW[i] = W1[i];
    __syncthreads();
    int lane = threadIdx.x & 63;
    int wid  = (blockIdx.x * 256 + threadIdx.x) >> 6;
    int nw   = (gridDim.x * 256) >> 6;
    for (int gidx = wid; gidx < NG; gidx += nw) {
        float ic = 1.0f / fmaxf(cntg[gidx], 1.0f);
        float acc = 0.0f;
#pragma unroll
        for (int k = 0; k < 64; ++k)
            acc = fmaf(pool[(size_t)gidx * 64 + k], sW[k * 64 + lane], acc);
        out[(size_t)gidx * 64 + lane] = fmaf(acc, ic, b1[lane]);
    }
}

extern "C" void kernel_launch(void* const* d_in, const int* in_sizes, int n_in,
                              void* d_out, int out_size, void* d_ws, size_t ws_size,
                              hipStream_t stream) {
    const float* x     = (const float*)d_in[0];
    const int*   ei    = (const int*)d_in[1];   // [2,E]
    const int*   batch = (const int*)d_in[3];
    const float* W0    = (const float*)d_in[4];
    const float* b0    = (const float*)d_in[5];
    const float* Wl    = (const float*)d_in[6];
    const float* bl    = (const float*)d_in[7];
    const float* Wr    = (const float*)d_in[8];
    const float* W1    = (const float*)d_in[9];
    const float* b1    = (const float*)d_in[10];
    float* out = (float*)d_out;

    char* ws = (char*)d_ws;
    size_t off = 0;
    auto alloc = [&](size_t bytes) -> void* {
        void* p = ws + off;
        off += (bytes + 255) & ~(size_t)255;
        return p;
    };
    float*          A      = (float*)alloc((size_t)NN * 64 * 4);          // h / r / h'
    __hip_bfloat16* G      = (__hip_bfloat16*)alloc((size_t)NN * 64 * 2); // g = h@Wl (bf16)
    int*            ell    = (int*)alloc((size_t)NN * MAXD * 4);          // ELL col
    unsigned int*   bucket = (unsigned int*)alloc((size_t)NBUK * BCAP * 4);
    int*            cnt    = (int*)alloc((size_t)NN * 4);                 // written, no memset
    // zero region: cursor + pool + cntg contiguous
    size_t zstart = off;
    int*   cursor = (int*)alloc((size_t)NBUK * 4);
    float* pool   = (float*)alloc((size_t)NG * 64 * 4);
    float* cntg   = (float*)alloc((size_t)NG * 4);
    size_t zlen = off - zstart;

    const int* src = ei;
    const int* dst = ei + NE;

    hipMemsetAsync(ws + zstart, 0, zlen, stream);

    // adjacency build: 2-phase binned, no global data atomics
    k_bin1<<<NBUK, 512, 0, stream>>>(src, dst, cursor, bucket);
    k_bin2<<<NBUK, 256, 0, stream>>>(bucket, cursor, cnt, ell);

    // input projection
    k_in_gemm<<<1024, 512, 0, stream>>>(x, W0, b0, A);

    // 3 SAGE layers: dense transform, then sparse gather
    for (int l = 0; l < 3; ++l) {
        k_gemmLR<<<1024, 256, 0, stream>>>(A, G,
                                           Wl + (size_t)l * 64 * 64,
                                           bl + (size_t)l * 64,
                                           Wr + (size_t)l * 64 * 64);
        k_gather<<<2048, 256, 0, stream>>>((const unsigned int*)G, A, cnt, ell);
    }

    k_pool<<<256, 256, 0, stream>>>(batch, A, pool, cntg);
    k_out<<<128, 256, 0, stream>>>(pool, cntg, W1, b1, out);
}

// Round 8
// 521.850 us; speedup vs baseline: 1.3253x; 1.1975x over previous
//
#include <hip/hip_runtime.h>
#include <hip/hip_bf16.h>

#define NN 100000
#define NE 1600000
#define DIN 128
#define NG 512
#define MAXD 64
#define NBUK 391               // dst>>8 buckets (256 nodes each)
#define BCAP 5120              // mean 4092, +16 sigma
#define CHUNK ((NE + NBUK - 1) / NBUK)

// ============ fused: phase-1 binning (blocks 0..NBUK) || input GEMM (rest) ============
#define GB 512
__global__ void __launch_bounds__(512) k_front(const int* __restrict__ src,
                                               const int* __restrict__ dst,
                                               int* __restrict__ cursor,
                                               unsigned int* __restrict__ bucket,
                                               const float* __restrict__ x,
                                               const float* __restrict__ W0,
                                               const float* __restrict__ b0,
                                               float* __restrict__ h) {
    __shared__ float sW[DIN * 64];
    __shared__ int lcnt[NBUK];
    __shared__ int lbase[NBUK];
    if (blockIdx.x < NBUK) {
        // ---- bin edges by dst>>8 via LDS histogram; 1 global atomic per (block,bucket) ----
        for (int i = threadIdx.x; i < NBUK; i += 512) lcnt[i] = 0;
        __syncthreads();
        int e0 = blockIdx.x * CHUNK;
        int e1 = min(e0 + CHUNK, NE);
        for (int e = e0 + (int)threadIdx.x; e < e1; e += 512)
            atomicAdd(&lcnt[dst[e] >> 8], 1);
        __syncthreads();
        for (int i = threadIdx.x; i < NBUK; i += 512) {
            int c = lcnt[i];
            lbase[i] = c ? atomicAdd(&cursor[i], c) : 0;
            lcnt[i] = 0;
        }
        __syncthreads();
        for (int e = e0 + (int)threadIdx.x; e < e1; e += 512) {
            int d = dst[e];
            int s = src[e];
            int bk = d >> 8;
            int pos = lbase[bk] + atomicAdd(&lcnt[bk], 1);
            if (pos < BCAP)
                bucket[(size_t)bk * BCAP + pos] = ((unsigned)s << 8) | (unsigned)(d & 255);
        }
    } else {
        // ---- input GEMM: h = relu(x @ W0 + b0), LDS weights, 2 nodes/wave ----
        for (int i = threadIdx.x; i < DIN * 64; i += 512) sW[i] = W0[i];
        __syncthreads();
        int lane = threadIdx.x & 63;
        int wv   = __builtin_amdgcn_readfirstlane(
                       (int)(((blockIdx.x - NBUK) * 512 + threadIdx.x) >> 6));
        int nw   = (GB * 512) >> 6;
        float bj = b0[lane];
        for (int p = wv; p < NN / 2; p += nw) {
            int n0 = 2 * p, n1 = n0 + 1;
            const float* x0 = x + (size_t)n0 * DIN;
            const float* x1 = x + (size_t)n1 * DIN;
            float acc0 = bj, acc1 = bj;
#pragma unroll 16
            for (int k = 0; k < DIN; ++k) {
                float wvl = sW[k * 64 + lane];
                acc0 = fmaf(x0[k], wvl, acc0);
                acc1 = fmaf(x1[k], wvl, acc1);
            }
            h[(size_t)n0 * 64 + lane] = fmaxf(acc0, 0.0f);
            h[(size_t)n1 * 64 + lane] = fmaxf(acc1, 0.0f);
        }
    }
}

// ============ phase 2: per-bucket ELL build; pre-fill slice with sentinel NN ============
__global__ void __launch_bounds__(256) k_bin2(const unsigned int* __restrict__ bucket,
                                              const int* __restrict__ cursor,
                                              int* __restrict__ cnt,
                                              int* __restrict__ ell) {
    __shared__ int lc[256];
    lc[threadIdx.x] = 0;
    int b = blockIdx.x;
    int4* ep = (int4*)(ell + (((size_t)b << 8) * MAXD));
    for (int i = threadIdx.x; i < (256 * MAXD) / 4; i += 256)
        ep[i] = make_int4(NN, NN, NN, NN);          // sentinel -> zero row of G
    __syncthreads();
    int m = min(cursor[b], BCAP);
    const unsigned int* bp = bucket + (size_t)b * BCAP;
    for (int i = threadIdx.x; i < m; i += 256) {
        unsigned v = bp[i];
        int dlo = (int)(v & 255u);
        int s   = (int)(v >> 8);
        int p   = atomicAdd(&lc[dlo], 1);           // LDS atomic
        if (p < MAXD)
            ell[(((size_t)b << 8) + dlo) * MAXD + p] = s;
    }
    __syncthreads();
    int n = (b << 8) + (int)threadIdx.x;
    if (n < NN) cnt[n] = lc[threadIdx.x];
}

// ============ gemmLR: g(bf16) = h@Wl ; r(fp32,in-place) = h@Wr + bl ============
// float2-packed weights in LDS (1 ds_read_b64 feeds both products), 4 nodes/wave.
__global__ void __launch_bounds__(256) k_gemmLR(float* __restrict__ h_r,
                                                __hip_bfloat16* __restrict__ g,
                                                const float* __restrict__ Wl,
                                                const float* __restrict__ bl,
                                                const float* __restrict__ Wr) {
    __shared__ float2 sW[64 * 64];
    for (int i = threadIdx.x; i < 64 * 64; i += 256)
        sW[i] = make_float2(Wl[i], Wr[i]);
    __syncthreads();
    int lane = threadIdx.x & 63;
    float bj = bl[lane];
    int wv = __builtin_amdgcn_readfirstlane((int)((blockIdx.x * 256 + threadIdx.x) >> 6));
    int nw = (gridDim.x * 256) >> 6;
    for (int q = wv; q < NN / 4; q += nw) {
        const float* hp = h_r + (size_t)(4 * q) * 64;   // wave-uniform -> s_load
        float l0 = 0, l1 = 0, l2 = 0, l3 = 0;
        float r0 = 0, r1 = 0, r2 = 0, r3 = 0;
#pragma unroll 16
        for (int k = 0; k < 64; ++k) {
            float2 w = sW[k * 64 + lane];
            float s0 = hp[k], s1 = hp[64 + k], s2 = hp[128 + k], s3 = hp[192 + k];
            l0 = fmaf(s0, w.x, l0); r0 = fmaf(s0, w.y, r0);
            l1 = fmaf(s1, w.x, l1); r1 = fmaf(s1, w.y, r1);
            l2 = fmaf(s2, w.x, l2); r2 = fmaf(s2, w.y, r2);
            l3 = fmaf(s3, w.x, l3); r3 = fmaf(s3, w.y, r3);
        }
        size_t base = (size_t)(4 * q) * 64 + lane;
        g[base]       = __float2bfloat16(l0);
        g[base + 64]  = __float2bfloat16(l1);
        g[base + 128] = __float2bfloat16(l2);
        g[base + 192] = __float2bfloat16(l3);
        h_r[base]       = r0 + bj;
        h_r[base + 64]  = r1 + bj;
        h_r[base + 128] = r2 + bj;
        h_r[base + 192] = r3 + bj;
    }
}

// ============ gather: 2 nodes/wave, 4 B/lane (bf16x2), sentinel-padded, branchless ====
__global__ void __launch_bounds__(256) k_gather(const unsigned int* __restrict__ g2,
                                                float* __restrict__ r_h,
                                                const int* __restrict__ cnt,
                                                const int* __restrict__ ell) {
    int lane = threadIdx.x & 63;
    int half = lane >> 5;
    int col  = lane & 31;
    int wv = __builtin_amdgcn_readfirstlane((int)((blockIdx.x * 256 + threadIdx.x) >> 6));
    int nw = (gridDim.x * 256) >> 6;
    for (int p = wv; p < NN / 2; p += nw) {
        int nA = 2 * p, nB = nA + 1;
        int dgA = cnt[nA], dgB = cnt[nB];               // wave-uniform scalar loads
        int myn  = half ? nB : nA;
        int mydg = half ? dgB : dgA;
        int maxd = min(max(dgA, dgB), MAXD);
        int iters = (maxd + 7) & ~7;                    // pad to 8; sentinels add 0
        // full index row (2x128B coalesced); slots beyond deg hold NN sentinel
        int idx0 = ell[(size_t)myn * MAXD + col];
        int idx1 = ell[(size_t)myn * MAXD + 32 + col];
        float L0 = 0.f, L1 = 0.f, L2 = 0.f, L3 = 0.f;
        float H0 = 0.f, H1 = 0.f, H2 = 0.f, H3 = 0.f;
        int it0 = min(iters, 32);
        for (int j = 0; j < it0; j += 4) {
            int i0 = __shfl(idx0, half * 32 + j);
            int i1 = __shfl(idx0, half * 32 + j + 1);
            int i2 = __shfl(idx0, half * 32 + j + 2);
            int i3 = __shfl(idx0, half * 32 + j + 3);
            unsigned u0 = g2[(size_t)i0 * 32 + col];
            unsigned u1 = g2[(size_t)i1 * 32 + col];
            unsigned u2 = g2[(size_t)i2 * 32 + col];
            unsigned u3 = g2[(size_t)i3 * 32 + col];
            L0 += __uint_as_float(u0 << 16); H0 += __uint_as_float(u0 & 0xffff0000u);
            L1 += __uint_as_float(u1 << 16); H1 += __uint_as_float(u1 & 0xffff0000u);
            L2 += __uint_as_float(u2 << 16); H2 += __uint_as_float(u2 & 0xffff0000u);
            L3 += __uint_as_float(u3 << 16); H3 += __uint_as_float(u3 & 0xffff0000u);
        }
        for (int j = 0; j < iters - 32; j += 4) {
            int i0 = __shfl(idx1, half * 32 + j);
            int i1 = __shfl(idx1, half * 32 + j + 1);
            int i2 = __shfl(idx1, half * 32 + j + 2);
            int i3 = __shfl(idx1, half * 32 + j + 3);
            unsigned u0 = g2[(size_t)i0 * 32 + col];
            unsigned u1 = g2[(size_t)i1 * 32 + col];
            unsigned u2 = g2[(size_t)i2 * 32 + col];
            unsigned u3 = g2[(size_t)i3 * 32 + col];
            L0 += __uint_as_float(u0 << 16); H0 += __uint_as_float(u0 & 0xffff0000u);
            L1 += __uint_as_float(u1 << 16); H1 += __uint_as_float(u1 & 0xffff0000u);
            L2 += __uint_as_float(u2 << 16); H2 += __uint_as_float(u2 & 0xffff0000u);
            L3 += __uint_as_float(u3 << 16); H3 += __uint_as_float(u3 & 0xffff0000u);
        }
        float inv  = 1.0f / fmaxf((float)mydg, 1.0f);
        float sumL = (L0 + L1) + (L2 + L3);
        float sumH = (H0 + H1) + (H2 + H3);
        float2* rp = (float2*)r_h + (size_t)myn * 32 + col;
        float2 rv = *rp;
        rv.x = fmaxf(fmaf(sumL, inv, rv.x), 0.0f);
        rv.y = fmaxf(fmaf(sumH, inv, rv.y), 0.0f);
        *rp = rv;
    }
}

// ============ pooling (batch sorted -> run accumulate) ============
__global__ void __launch_bounds__(256) k_pool(const int* __restrict__ batch,
                                              const float* __restrict__ h,
                                              float* __restrict__ pool,
                                              float* __restrict__ cntg) {
    int lane = threadIdx.x & 63;
    int wid  = (blockIdx.x * 256 + threadIdx.x) >> 6;
    int nw   = (gridDim.x * 256) >> 6;
    int chunk = (NN + nw - 1) / nw;
    int n0 = wid * chunk;
    if (n0 >= NN) return;
    int n1 = min(n0 + chunk, NN);
    int cur = batch[n0];
    float acc = 0.0f, acc_c = 0.0f;
    for (int n = n0; n < n1; ++n) {
        int b = batch[n];
        if (b != cur) {
            atomicAdd(&pool[(size_t)cur * 64 + lane], acc);
            if (lane == 0) atomicAdd(&cntg[cur], acc_c);
            acc = 0.0f; acc_c = 0.0f; cur = b;
        }
        acc   += h[(size_t)n * 64 + lane];
        acc_c += 1.0f;
    }
    atomicAdd(&pool[(size_t)cur * 64 + lane], acc);
    if (lane == 0) atomicAdd(&cntg[cur], acc_c);
}

// ============ output GEMM ============
__global__ void __launch_bounds__(256) k_out(const float* __restrict__ pool,
                                             const float* __restrict__ cntg,
                                             const float* __restrict__ W1,
                                             const float* __restrict__ b1,
                                             float* __restrict__ out) {
    __shared__ float sW[64 * 64];
    for (int i = threadIdx.x; i < 64 * 64; i += 256) sW[i] = W1[i];
    __syncthreads();
    int lane = threadIdx.x & 63;
    int wid  = (blockIdx.x * 256 + threadIdx.x) >> 6;
    int nw   = (gridDim.x * 256) >> 6;
    for (int gidx = wid; gidx < NG; gidx += nw) {
        float ic = 1.0f / fmaxf(cntg[gidx], 1.0f);
        float acc = 0.0f;
#pragma unroll
        for (int k = 0; k < 64; ++k)
            acc = fmaf(pool[(size_t)gidx * 64 + k], sW[k * 64 + lane], acc);
        out[(size_t)gidx * 64 + lane] = fmaf(acc, ic, b1[lane]);
    }
}

extern "C" void kernel_launch(void* const* d_in, const int* in_sizes, int n_in,
                              void* d_out, int out_size, void* d_ws, size_t ws_size,
                              hipStream_t stream) {
    const float* x     = (const float*)d_in[0];
    const int*   ei    = (const int*)d_in[1];   // [2,E]
    const int*   batch = (const int*)d_in[3];
    const float* W0    = (const float*)d_in[4];
    const float* b0    = (const float*)d_in[5];
    const float* Wl    = (const float*)d_in[6];
    const float* bl    = (const float*)d_in[7];
    const float* Wr    = (const float*)d_in[8];
    const float* W1    = (const float*)d_in[9];
    const float* b1    = (const float*)d_in[10];
    float* out = (float*)d_out;

    char* ws = (char*)d_ws;
    size_t off = 0;
    auto alloc = [&](size_t bytes) -> void* {
        void* p = ws + off;
        off += (bytes + 255) & ~(size_t)255;
        return p;
    };
    float*          A      = (float*)alloc((size_t)NN * 64 * 4);          // h / r / h'
    __hip_bfloat16* G      = (__hip_bfloat16*)alloc((size_t)NN * 64 * 2); // g (bf16), NN rows
    // zero region starts EXACTLY at G's row NN (sentinel zero row), then cursor/pool/cntg
    size_t zstart = off;
    (void)alloc((size_t)MAXD * 2);                                        // G zero row (128 B)
    int*   cursor = (int*)alloc((size_t)NBUK * 4);
    float* pool   = (float*)alloc((size_t)NG * 64 * 4);
    float* cntg   = (float*)alloc((size_t)NG * 4);
    size_t zlen = off - zstart;
    int*          ell    = (int*)alloc((size_t)NBUK * 256 * MAXD * 4);    // padded ELL
    unsigned int* bucket = (unsigned int*)alloc((size_t)NBUK * BCAP * 4);
    int*          cnt    = (int*)alloc((size_t)NN * 4);                   // fully written

    const int* src = ei;
    const int* dst = ei + NE;

    hipMemsetAsync(ws + zstart, 0, zlen, stream);

    // phase-1 binning || input projection (independent, block-partitioned)
    k_front<<<NBUK + GB, 512, 0, stream>>>(src, dst, cursor, bucket, x, W0, b0, A);
    // phase-2 ELL build (sentinel-padded, LDS atomics only)
    k_bin2<<<NBUK, 256, 0, stream>>>(bucket, cursor, cnt, ell);

    // 3 SAGE layers: dense transform, then sparse gather
    for (int l = 0; l < 3; ++l) {
        k_gemmLR<<<1024, 256, 0, stream>>>(A, G,
                                           Wl + (size_t)l * 64 * 64,
                                           bl + (size_t)l * 64,
                                           Wr + (size_t)l * 64 * 64);
        k_gather<<<2048, 256, 0, stream>>>((const unsigned int*)G, A, cnt, ell);
    }

    k_pool<<<256, 256, 0, stream>>>(batch, A, pool, cntg);
    k_out<<<128, 256, 0, stream>>>(pool, cntg, W1, b1, out);
}